// Round 1
// baseline (39.573 us; speedup 1.0000x reference)
//
#include <hip/hip_runtime.h>
#include <math.h>

#define BB 64
#define AA 32
#define KK 50
#define DD 128
#define MAX_KP 50
#define EPS_CS 1e-8f

// One block (128 threads) per (tensor, b, a) vector: gather K rows, mean-pool,
// L2-normalize, write normalized vector to ws.
__global__ void embed_norm_kernel(const int* __restrict__ src,
                                  const int* __restrict__ pos,
                                  const int* __restrict__ neg,
                                  const float* __restrict__ table,
                                  float* __restrict__ out /* [3][BB][AA][DD] */)
{
    const int vec = blockIdx.x;          // 0 .. 3*BB*AA-1 (6144)
    const int t  = vec >> 11;            // / (BB*AA = 2048)
    const int ba = vec & 2047;

    const int* idx_base = (t == 0) ? src : (t == 1) ? pos : neg;
    idx_base += ba * KK;

    const int d = threadIdx.x;           // 0..127
    float acc = 0.f;
    #pragma unroll
    for (int k = 0; k < KK; ++k) {
        const int row = idx_base[k];     // wave-uniform scalar load
        acc += table[(long)row * DD + d];  // coalesced 512B row read
    }
    acc *= (1.0f / MAX_KP);

    // sum of squares over 128 threads (2 waves)
    float sq = acc * acc;
    #pragma unroll
    for (int off = 32; off > 0; off >>= 1) sq += __shfl_down(sq, off, 64);

    __shared__ float partial[2];
    const int wave = threadIdx.x >> 6;
    if ((threadIdx.x & 63) == 0) partial[wave] = sq;
    __syncthreads();
    const float n2 = partial[0] + partial[1];
    const float nrm = sqrtf(n2);
    const float inv = 1.0f / fmaxf(nrm, EPS_CS);

    out[(long)vec * DD + d] = acc * inv;
}

// One block (256 threads) per batch: max cosine over 32x32 pairs for pos and
// neg, then per-batch softplus(-(pos-neg)).
__global__ void cosine_loss_kernel(const float* __restrict__ embs,
                                   float* __restrict__ per_batch /* [BB] */)
{
    const int b = blockIdx.x;
    // Pad inner dim to 129 floats: breaks the 32-way bank conflict on the
    // s_*[j][d] read (stride 128 ≡ 0 mod 32 banks).
    __shared__ float s_src[AA][DD + 1];
    __shared__ float s_pos[AA][DD + 1];
    __shared__ float s_neg[AA][DD + 1];

    const long base = (long)b * AA * DD;
    const float* src = embs + base;
    const float* pos = embs + (long)BB * AA * DD + base;
    const float* neg = embs + 2L * BB * AA * DD + base;

    const int tid = threadIdx.x;         // 0..255
    for (int i = tid; i < AA * DD; i += 256) {
        const int r = i >> 7, c = i & 127;
        s_src[r][c] = src[i];
        s_pos[r][c] = pos[i];
        s_neg[r][c] = neg[i];
    }
    __syncthreads();

    float pmax = -1e30f, nmax = -1e30f;
    #pragma unroll
    for (int p = 0; p < 4; ++p) {
        const int pair = tid + p * 256;  // 0..1023
        const int i = pair >> 5;
        const int j = pair & 31;
        float dp = 0.f, dn = 0.f;
        #pragma unroll 8
        for (int d = 0; d < DD; ++d) {
            const float s = s_src[i][d];
            dp += s * s_pos[j][d];
            dn += s * s_neg[j][d];
        }
        pmax = fmaxf(pmax, dp);
        nmax = fmaxf(nmax, dn);
    }

    #pragma unroll
    for (int off = 32; off > 0; off >>= 1) {
        pmax = fmaxf(pmax, __shfl_down(pmax, off, 64));
        nmax = fmaxf(nmax, __shfl_down(nmax, off, 64));
    }
    __shared__ float sp[4], sn[4];
    const int wave = tid >> 6;
    if ((tid & 63) == 0) { sp[wave] = pmax; sn[wave] = nmax; }
    __syncthreads();

    if (tid == 0) {
        const float P = fmaxf(fmaxf(sp[0], sp[1]), fmaxf(sp[2], sp[3]));
        const float N = fmaxf(fmaxf(sn[0], sn[1]), fmaxf(sn[2], sn[3]));
        const float x = P - N;
        // softplus(-x), numerically stable
        const float l = (x >= 0.f) ? log1pf(expf(-x)) : (-x + log1pf(expf(x)));
        per_batch[b] = l;
    }
}

__global__ void mean_kernel(const float* __restrict__ per_batch,
                            float* __restrict__ out)
{
    const int tid = threadIdx.x;         // 0..63
    float v = per_batch[tid];
    #pragma unroll
    for (int off = 32; off > 0; off >>= 1) v += __shfl_down(v, off, 64);
    if (tid == 0) out[0] = v * (1.0f / BB);
}

extern "C" void kernel_launch(void* const* d_in, const int* in_sizes, int n_in,
                              void* d_out, int out_size, void* d_ws, size_t ws_size,
                              hipStream_t stream) {
    const int*   batch_source = (const int*)d_in[0];
    const int*   pos_result   = (const int*)d_in[1];
    const int*   neg_result   = (const int*)d_in[2];
    const float* emb_table    = (const float*)d_in[3];
    float* out = (float*)d_out;

    float* embs      = (float*)d_ws;                       // 3*64*32*128 floats = 3 MB
    float* per_batch = embs + 3L * BB * AA * DD;           // 64 floats

    embed_norm_kernel<<<3 * BB * AA, DD, 0, stream>>>(
        batch_source, pos_result, neg_result, emb_table, embs);
    cosine_loss_kernel<<<BB, 256, 0, stream>>>(embs, per_batch);
    mean_kernel<<<1, 64, 0, stream>>>(per_batch, out);
}